// Round 10
// baseline (79.287 us; speedup 1.0000x reference)
//
#include <hip/hip_runtime.h>

#define BB 32
#define QQ 16384
#define GG 128
#define KK 32
#define NN 9
#define TT 8      // GTs per block; tail waves 0..7, waves 8..15 exit early
#define TH 1024   // 16 waves; 512 blocks -> 2 blocks/CU
#define RR (QQ / TH)  // 16 elements per thread-range
#define NW (TH / 64)
#define CAP 192   // per-GT candidate capacity (expected ~40 with tight U)
#define ACAP 96   // per-GT active-range capacity (expected ~36)
#define UF 4      // load prefetch batch

typedef unsigned long long u64;
typedef unsigned int u32;

#define INFF __uint_as_float(0x7F800000u)

// packed ascending key: (float bits of nonneg key) << 32 | idx
// lexicographic u64 compare == (value asc, index asc) == jax top_k tie rule
__device__ __forceinline__ u64 pack_asc(float key, u32 idx) {
  return (((u64)__float_as_uint(key)) << 32) | (u64)idx;
}

// EXACT reference squared distance: ((dx^2+dy^2)+dz^2)+dw^2, no contraction.
// ref d = sqrtf(this).
__device__ __forceinline__ float dist2_ref(const float4 g, const float4 p) {
#pragma clang fp contract(off)
  float dx = g.x - p.x;
  float dy = g.y - p.y;
  float dz = g.z - p.z;
  float dw = g.w - p.w;
  float s = dx * dx + dy * dy;
  s = s + dz * dz;
  s = s + dw * dw;
  return s;
}

// IoU exactly as reference (cxcywh -> xyxy, clip, same op order)
__device__ __forceinline__ float iou_ref(const float4 g, const float4 p) {
#pragma clang fp contract(off)
  float gx1 = g.x - 0.5f * g.z, gy1 = g.y - 0.5f * g.w;
  float gx2 = g.x + 0.5f * g.z, gy2 = g.y + 0.5f * g.w;
  float px1 = p.x - 0.5f * p.z, py1 = p.y - 0.5f * p.w;
  float px2 = p.x + 0.5f * p.z, py2 = p.y + 0.5f * p.w;
  float ltx = fmaxf(gx1, px1), lty = fmaxf(gy1, py1);
  float rbx = fminf(gx2, px2), rby = fminf(gy2, py2);
  float wx = fmaxf(rbx - ltx, 0.0f), wy = fmaxf(rby - lty, 0.0f);
  float inter = wx * wy;
  float aa = (gx2 - gx1) * (gy2 - gy1);
  float ab = (px2 - px1) * (py2 - py1);
  return inter / ((aa + ab) - inter);
}

// full ascending bitonic sort across one 64-lane wave, u64 keys
__device__ __forceinline__ u64 bitonic64(u64 v, int lane) {
#pragma unroll
  for (int k = 2; k <= 64; k <<= 1) {
#pragma unroll
    for (int j = k >> 1; j > 0; j >>= 1) {
      u64 o = __shfl_xor(v, j, 64);
      bool up = ((lane & k) == 0);
      bool lower = ((lane & j) == 0);
      v = (lower == up) ? (v < o ? v : o) : (v > o ? v : o);
    }
  }
  return v;
}

// full ascending bitonic sort across one 64-lane wave, float keys
// (handles negatives; values finite or +inf padding, never NaN)
__device__ __forceinline__ float bitonic64f(float v, int lane) {
#pragma unroll
  for (int k = 2; k <= 64; k <<= 1) {
#pragma unroll
    for (int j = k >> 1; j > 0; j >>= 1) {
      float o = __shfl_xor(v, j, 64);
      bool up = ((lane & k) == 0);
      bool lower = ((lane & j) == 0);
      v = (lower == up) ? fminf(v, o) : fmaxf(v, o);
    }
  }
  return v;
}

__global__ __launch_bounds__(TH, 8) void atss_kernel(
    const float4* __restrict__ pred, const float4* __restrict__ gtb,
    int* __restrict__ out) {
  __shared__ float smin[TT][TH];            // 32 KB
  __shared__ float ckey[TT][CAP];           // 6 KB
  __shared__ unsigned short cidx[TT][CAP];  // 3 KB
  __shared__ unsigned short sact[TT][ACAP]; // 1.5 KB
  __shared__ int kidx[TT][KK];              // 1 KB
  __shared__ int nC[TT];
  __shared__ int nAct[TT];

  const int t = threadIdx.x;
  // XCD swizzle (round-robin block->XCD assumed): the 16 blocks of one
  // batch share an XCD; its L2 holds that batch's 256 KB pred slice.
  const int f = blockIdx.x;
  const int b = (f & 7) * 4 + (f >> 7);
  const int g0 = ((f >> 3) & 15) * TT;

  if (t < TT) {
    nC[t] = 0;
    nAct[t] = 0;
  }

  // 8 GT boxes from block-uniform addresses -> scalar loads / SGPRs
  float4 G[TT];
#pragma unroll
  for (int gg = 0; gg < TT; ++gg) G[gg] = gtb[b * GG + g0 + gg];

  const float4* pb = pred + (size_t)b * QQ;

  // ---- pass 1: per-thread min of s = |p|^2 - 2 g.p over 16 elements ----
  // (d2 shifted by per-GT constant -|g|^2 -> same ordering). One float4
  // load feeds 8 GTs; 4 loads in flight; element-paired min update so the
  // compiler emits v_min3_f32 (1 min instr per 2 elements).
  float mn[TT];
#pragma unroll
  for (int gg = 0; gg < TT; ++gg) mn[gg] = INFF;

  float4 P[UF];
#pragma unroll
  for (int u = 0; u < UF; ++u) P[u] = pb[t + u * TH];
#pragma unroll
  for (int j = 0; j < RR; j += UF) {
    float4 C[UF];
#pragma unroll
    for (int u = 0; u < UF; ++u) C[u] = P[u];
    if (j + UF < RR) {
#pragma unroll
      for (int u = 0; u < UF; ++u) P[u] = pb[t + (j + UF + u) * TH];
    }
#pragma unroll
    for (int u = 0; u < UF; u += 2) {
      float4 qa = C[u], qb = C[u + 1];
      float ppa = fmaf(qa.x, qa.x, fmaf(qa.y, qa.y, fmaf(qa.z, qa.z, qa.w * qa.w)));
      float ppb = fmaf(qb.x, qb.x, fmaf(qb.y, qb.y, fmaf(qb.z, qb.z, qb.w * qb.w)));
#pragma unroll
      for (int gg = 0; gg < TT; ++gg) {
        float da = fmaf(G[gg].x, qa.x,
                   fmaf(G[gg].y, qa.y,
                   fmaf(G[gg].z, qa.z, G[gg].w * qa.w)));
        float db = fmaf(G[gg].x, qb.x,
                   fmaf(G[gg].y, qb.y,
                   fmaf(G[gg].z, qb.z, G[gg].w * qb.w)));
        float sa = fmaf(-2.0f, da, ppa);
        float sb = fmaf(-2.0f, db, ppb);
        mn[gg] = fminf(fminf(mn[gg], sa), sb);  // -> v_min3_f32
      }
    }
  }
#pragma unroll
  for (int gg = 0; gg < TT; ++gg) smin[gg][t] = mn[gg];

  __syncthreads();  // the ONLY block-wide barrier

  const int w = t >> 6;
  const int lane = t & 63;
  if (w >= TT) return;  // waves 8..15 done; frees wave slots

  // ================= wave w handles GT (g0 + w) alone =================
  const float4 gt = gtb[b * GG + g0 + w];  // wave-uniform reload

  // ---- load this GT's 1024 thread-mins; lane owns threads {lane + 64k}
  // (conflict-free stride-4B ds reads; a disjoint range partition).
  float V[NW];
#pragma unroll
  for (int k = 0; k < NW; ++k) V[k] = smin[w][lane + 64 * k];

  // ---- per-lane 2 smallest of its 16 values (branchless) ----
  float m1 = INFF, m2 = INFF;
#pragma unroll
  for (int k = 0; k < NW; ++k) {
    float v = V[k];
    float nm1 = fminf(m1, v);
    m2 = fminf(m2, fmaxf(m1, v));
    m1 = nm1;
  }

  // ---- U = 32nd smallest of the 128 kept values (2 per lane) ----
  // Kept set is a subset of the 1024 thread-mins -> its 32nd smallest is
  // >= the true 32nd smallest thread-min; the 32 kept values <= U are 32
  // DISTINCT threads' range-mins -> >= 32 distinct elements have approx
  // s <= U. Tight: E[n] ~36, P(n>64) ~0 (proven R9: -16 us vs loose bound).
  float A = bitonic64f(m1, lane);
  float Bs = bitonic64f(m2, lane);
  float Br = __shfl(Bs, 63 - lane, 64);  // descending B
  float m = fminf(A, Br);  // bitonic sequence holding the 64 smallest
#pragma unroll
  for (int j = 32; j > 0; j >>= 1) {  // sort bitonic -> ascending
    float o = __shfl_xor(m, j, 64);
    m = ((lane & j) == 0) ? fminf(m, o) : fmaxf(m, o);
  }
  float Us = __shfl(m, 31, 64);  // 32nd smallest, wave-uniform
  float gg2 = fmaf(gt.x, gt.x,
              fmaf(gt.y, gt.y, fmaf(gt.z, gt.z, gt.w * gt.w)));
  // Inflation covers fma-form vs ref-form rounding (~5e-7 abs) and
  // sqrt-collapse ties (margins proven in R5-R9).
  const float sUs = Us + fabsf(Us) * 2e-5f + 4e-6f;          // s-space test
  const float T = fmaxf(Us + gg2, 0.0f) * 1.00002f + 4e-6f;  // d2-space test

  // ---- compact active ranges (expected ~36 of 1024) ----
#pragma unroll
  for (int k = 0; k < NW; ++k) {
    if (V[k] <= sUs) {
      int pos = atomicAdd(&nAct[w], 1);
      if (pos < ACAP) sact[w][pos] = (unsigned short)(lane + 64 * k);
    }
  }
  int na = nAct[w];  // same-wave DS ordering: no barrier needed

  // ---- exact-d2 collection, flattened over (range x element) ----
  // All 64 lanes busy; iterations independent -> loads overlap instead of
  // the old 16-serial-L2-latency walk per active lane.
  if (na <= ACAP) {
    int tot = na * RR;
    for (int e = lane; e < tot; e += 64) {
      int r = sact[w][e >> 4];           // RR == 16
      int i = r + (e & (RR - 1)) * TH;
      float d2 = dist2_ref(gt, pb[i]);
      if (d2 <= T) {
        int pos = atomicAdd(&nC[w], 1);
        if (pos < CAP) {
          ckey[w][pos] = d2;
          cidx[w][pos] = (unsigned short)i;
        }
      }
    }
  } else {
    // pathological: dense wave rescan of all ranges
    for (int r = lane; r < TH; r += 64) {
      for (int j = 0; j < RR; ++j) {
        int i = r + j * TH;
        float d2 = dist2_ref(gt, pb[i]);
        if (d2 <= T) {
          int pos = atomicAdd(&nC[w], 1);
          if (pos < CAP) {
            ckey[w][pos] = d2;
            cidx[w][pos] = (unsigned short)i;
          }
        }
      }
    }
  }
  int n = nC[w];  // >= 32 guaranteed by the bound argument

  // ---- select top-32 by (d, idx) ascending; d = sqrtf(d2) (IEEE == jnp)
  if (n > CAP) {
    // pathological-only exact serial fallback
    if (lane == 0) {
      u64 best[KK];
      for (int l = 0; l < KK; ++l) best[l] = ~0ull;
      for (int i = 0; i < QQ; ++i) {
        float d = sqrtf(dist2_ref(gt, pb[i]));
        u64 pk = pack_asc(d, (u32)i);
        if (pk < best[KK - 1]) {
          int pos = KK - 1;
          while (pos > 0 && best[pos - 1] > pk) {
            best[pos] = best[pos - 1];
            --pos;
          }
          best[pos] = pk;
        }
      }
      for (int l = 0; l < KK; ++l) kidx[w][l] = (int)(best[l] & 0xFFFFFFFFull);
    }
  } else if (n <= 64) {
    // fast path (~100% with tight U): one wave bitonic sort
    u64 v = (lane < n) ? pack_asc(sqrtf(ckey[w][lane]), (u32)cidx[w][lane])
                       : ~0ull;
    u64 s = bitonic64(v, lane);
    if (lane < KK) kidx[w][lane] = (int)(s & 0xFFFFFFFFull);
  } else {
    // 64 < n <= CAP: 32 rounds of wave-wide argmin extraction (rare)
    volatile float* vk = ckey[w];
    for (int sel = 0; sel < KK; ++sel) {
      u64 lm = ~0ull;
      int ls = -1;
      for (int s = lane; s < n; s += 64) {
        float d = sqrtf(vk[s]);  // sqrtf(inf)=inf for consumed slots
        u64 pk = pack_asc(d, (u32)cidx[w][s]);
        if (pk < lm) {
          lm = pk;
          ls = s;
        }
      }
      u64 ww = lm;
#pragma unroll
      for (int j = 32; j > 0; j >>= 1) {
        u64 o = __shfl_xor(ww, j, 64);
        ww = o < ww ? o : ww;
      }
      if (lm == ww && ls >= 0) {  // unique winner (idx unique)
        vk[ls] = INFF;            // mark used
        kidx[w][sel] = (int)(ww & 0xFFFFFFFFull);
      }
    }
  }
  // same-wave DS ordering: kidx[w] writes visible to this wave's reads

  // ---- IoU of the 32 candidates, top-9 by (iou desc, position asc) ----
  {
    u64 v = ~0ull;
    if (lane < KK) {
      float iou = iou_ref(gt, pb[kidx[w][lane]]);
      // ~bits(iou) strictly decreasing in iou (iou >= 0): ascending packed
      // sort == descending iou, ties -> lower K-position first
      v = (((u64)(~__float_as_uint(iou))) << 32) | (u64)lane;
    }
    u64 s = bitonic64(v, lane);
    if (lane < NN) {
      int pos = (int)(s & 0xFFFFFFFFull);
      int base = (b * GG + g0 + w) * NN + lane;
      out[base] = kidx[w][pos];           // pred_idx
      out[BB * GG * NN + base] = g0 + w;  // gt_idx
    }
  }
}

extern "C" void kernel_launch(void* const* d_in, const int* in_sizes, int n_in,
                              void* d_out, int out_size, void* d_ws, size_t ws_size,
                              hipStream_t stream) {
  (void)in_sizes;
  (void)n_in;
  (void)out_size;
  (void)d_ws;
  (void)ws_size;
  const float4* pred = (const float4*)d_in[0];  // [B, Q, 4] f32
  const float4* gt = (const float4*)d_in[1];    // [B, G, 4] f32
  int* out = (int*)d_out;                       // [2 * B * G * N] int32
  atss_kernel<<<(GG / TT) * BB, TH, 0, stream>>>(pred, gt, out);
}